// Round 7
// baseline (34866.602 us; speedup 1.0000x reference)
//
#include <hip/hip_runtime.h>

#define NWG 256
#define NT  512
#define B_  64
#define T_  128
#define U_  1024
#define C3  3072

// Padded U/W column: 16 chunks of (64+4) floats -> kq slices land on distinct banks
#define COLSTRIDE 1088
#define U_LDS_FLOATS (24*COLSTRIDE)
#define P_OFF   U_LDS_FLOATS                 // P: [24 dc][4 kh][64 b] = 6144 floats
#define REC_OFF (P_OFF + 6144)               // rec: 1536 floats
#define SMEM_BYTES ((U_LDS_FLOATS + 6144 + 1536)*4)   // 135168 B -> 1 WG/CU, 8 waves

// ws layout (floats)
#define XPV_OFF  0
#define EMBT_OFF (6144*128)
#define HG_OFF   (EMBT_OFF + 1024*128)
#define CTR_OFF  (HG_OFF + 2*2*1024*64)      // barrier counter (uint), byte off = CTR_OFF*4

typedef float f32x4 __attribute__((ext_vector_type(4)));

__device__ __forceinline__ float sigm(float x){ return 1.f/(1.f+__expf(-x)); }
__device__ __forceinline__ float tanh_(float x){ return 1.f - 2.f/(1.f+__expf(2.f*x)); }

// ---- L3-coherent (L1/L2-bypassing) access: the ONLY cross-WG steady-state data is h ----
__device__ __forceinline__ void ld_issue(f32x4& d, const float* p){
  asm volatile("global_load_dwordx4 %0, %1, off sc0 sc1" : "=v"(d) : "v"(p));
}
template<int N>
__device__ __forceinline__ void wait_vm4(f32x4& a, f32x4& b, f32x4& c, f32x4& d){
  asm volatile("s_waitcnt vmcnt(%4)" : "+v"(a),"+v"(b),"+v"(c),"+v"(d) : "n"(N));
  __builtin_amdgcn_sched_barrier(0);
}
__device__ __forceinline__ void st_coh(float* p, float v){
  asm volatile("global_store_dword %0, %1, off sc0 sc1" :: "v"(p), "v"(v) : "memory");
}

// Fence-free grid barrier. The EXPLICIT vmcnt drain is required: the compiler's
// auto-waitcnt before s_barrier does NOT track inline-asm memory ops, so without
// it the sc0sc1 h-stores may still be in flight when the leader arrives.
__device__ __forceinline__ void wg_barrier(unsigned* ctr, unsigned target){
  asm volatile("s_waitcnt vmcnt(0) lgkmcnt(0)" ::: "memory");
  __syncthreads();
  if (threadIdx.x == 0){
    __hip_atomic_fetch_add(ctr, 1u, __ATOMIC_RELAXED, __HIP_MEMORY_SCOPE_AGENT);
    while (__hip_atomic_load(ctr, __ATOMIC_RELAXED, __HIP_MEMORY_SCOPE_AGENT) < target)
      __builtin_amdgcn_s_sleep(1);
  }
  __syncthreads();
  asm volatile("" ::: "memory");
}

__global__ void __launch_bounds__(NT, 2)
enc_kernel(const int* __restrict__ tok,
           const float* __restrict__ emb,
           const float* __restrict__ Wf, const float* __restrict__ Uf, const float* __restrict__ bfp,
           const float* __restrict__ Wb, const float* __restrict__ Ub, const float* __restrict__ bbp,
           float* __restrict__ out, float* __restrict__ ws)
{
  extern __shared__ float sm[];
  float* Ul   = sm;
  float* Pl   = sm + P_OFF;
  float* recl = sm + REC_OFF;

  const int tid = threadIdx.x, wg = blockIdx.x;
  const int u0 = wg*4;

  float* xpv  = ws + XPV_OFF;                // [2d*3072 c][128 v]
  float* embT = ws + EMBT_OFF;               // [1024 k][128 v]
  float* hg   = ws + HG_OFF;                 // [2 buf][2 d][1024 u][64 b]
  unsigned* ctr = (unsigned*)(ws + CTR_OFF);

  // ---- prologue: zero h buf0, transpose emb -> embT (both published via sc0sc1) ----
  const int gtid = wg*NT + tid;
  for (int i = gtid; i < 2*1024*64; i += NWG*NT) st_coh(&hg[i], 0.f);
  for (int i = gtid; i < 128*1024; i += NWG*NT)
    st_coh(&embT[(i & 1023)*128 + (i >> 10)], emb[i]);

  auto loadMat = [&](const float* Mf_, const float* Mb_) {
    #pragma unroll
    for (int i = 0; i < 12; ++i) {
      int flat = tid + i*NT;
      int k = flat / 6, rem = flat % 6;
      int dd = rem / 3, g = rem % 3;
      const float* M = dd ? Mb_ : Mf_;
      f32x4 v4 = *(const f32x4*)&M[k*C3 + g*U_ + u0];
      int koff = (k >> 6)*68 + (k & 63);
      Ul[(dd*12 + 0*3 + g)*COLSTRIDE + koff] = v4.x;
      Ul[(dd*12 + 1*3 + g)*COLSTRIDE + koff] = v4.y;
      Ul[(dd*12 + 2*3 + g)*COLSTRIDE + koff] = v4.z;
      Ul[(dd*12 + 3*3 + g)*COLSTRIDE + koff] = v4.w;
    }
  };

  unsigned bar = 0;
  loadMat(Wf, Wb);
  wg_barrier(ctr, (++bar)*NWG);              // embT + h0 at L3; W in LDS

  // ---- wave identity ----
  const int lane = tid & 63, wv = tid >> 6;
  const int d = wv >> 2, kh = wv & 3;
  const int bq = lane & 15, kq = lane >> 4;
  const float* ubase = Ul + (d*12)*COLSTRIDE + (kh*4 + kq)*68;

  // 12 cols x 4 rows/lane over this wave's 256-k quarter; pipelined sc0sc1 h loads.
  auto dot12 = [&](const float* src, int rs, float* r) {
    f32x4 acc[12];
    #pragma unroll
    for (int j=0;j<12;++j) acc[j] = (f32x4)0.f;
    f32x4 hb[2][4];
    #pragma unroll
    for (int c=0;c<4;++c) ld_issue(hb[0][c], src + c*rs);
    #pragma unroll
    for (int kit=0; kit<16; ++kit){
      const int cur = kit & 1;
      f32x4 uv[12];
      #pragma unroll
      for (int j=0;j<12;++j) uv[j] = *(const f32x4*)(ubase + j*COLSTRIDE + kit*4);
      if (kit < 15){
        #pragma unroll
        for (int c=0;c<4;++c) ld_issue(hb[cur^1][c], src + ((kit+1)*4+c)*rs);
        wait_vm4<4>(hb[cur][0],hb[cur][1],hb[cur][2],hb[cur][3]);
      } else {
        wait_vm4<0>(hb[cur][0],hb[cur][1],hb[cur][2],hb[cur][3]);
      }
      #pragma unroll
      for (int kk=0;kk<4;++kk){
        f32x4 h4 = hb[cur][kk];
        #pragma unroll
        for (int j=0;j<12;++j) acc[j] += h4 * uv[j][kk];
      }
    }
    #pragma unroll
    for (int j=0;j<12;++j){
      #pragma unroll
      for (int bi=0;bi<4;++bi){
        float v = acc[j][bi];
        v += __shfl_xor(v, 16, 64);
        v += __shfl_xor(v, 32, 64);
        acc[j][bi] = v;
      }
      r[j] = kq==0?acc[j][0] : kq==1?acc[j][1] : kq==2?acc[j][2] : acc[j][3];
    }
  };

  // ---- phase A: xpv[c][v] = emb@W + b0 ----
  for (int half = 0; half < 2; ++half) {
    float r[12];
    dot12(embT + (kh*256 + kq*64)*128 + half*64 + bq*4, 128, r);
    const int vv = bq*4 + kq;
    #pragma unroll
    for (int j=0;j<12;++j) Pl[(d*12+j)*256 + kh*64 + vv] = r[j];
    __syncthreads();
    for (int e = tid; e < 1536; e += NT) {
      int dc = e >> 6, v = e & 63;
      float s_ = Pl[dc*256 + v] + Pl[dc*256 + 64 + v] + Pl[dc*256 + 128 + v] + Pl[dc*256 + 192 + v];
      int dd = dc / 12, c = dc % 12;
      int ul = c / 3, g = c % 3;
      int cp = g*U_ + u0 + ul;
      const float* brow = dd ? bbp : bfp;
      st_coh(&xpv[(dd*C3 + cp)*128 + half*64 + v], s_ + brow[cp]);
    }
    __syncthreads();
  }
  wg_barrier(ctr, (++bar)*NWG);              // xpv at L3; readers will L2-cache it

  loadMat(Uf, Ub);
  __syncthreads();

  // gate-phase identity + persistent h register (this thread owns (gd,gu,gb) forever)
  const int gd = tid >> 8, grm = tid & 255, gb = grm >> 2, gul = grm & 3;
  const int gu = u0 + gul;
  const float* brow1 = (gd ? bbp : bfp) + C3;
  const float bz1 = brow1[gu], br1 = brow1[U_ + gu], bh1 = brow1[2*U_ + gu];
  float hprev = 0.f;

  // ---- recurrence: 128 lockstep steps, light barrier, L2 never invalidated ----
  for (int s = 0; s < T_; ++s) {
    const float* hc = hg + (s&1)*(2*1024*64);
    float*       hn = hg + ((s+1)&1)*(2*1024*64);

    float r[12];
    dot12(hc + (d*1024 + kh*256 + kq*64)*64 + bq*4, 64, r);
    const int b = bq*4 + kq;
    #pragma unroll
    for (int j=0;j<12;++j) Pl[(d*12+j)*256 + kh*64 + b] = r[j];
    __syncthreads();

    #pragma unroll
    for (int e = tid, it = 0; it < 3; ++it, e += NT) {
      int dc = e >> 6, v = e & 63;
      recl[e] = Pl[dc*256 + v] + Pl[dc*256 + 64 + v] + Pl[dc*256 + 128 + v] + Pl[dc*256 + 192 + v];
    }
    __syncthreads();

    {
      const int t = gd ? (T_-1 - s) : s;
      const int tk = tok[gb*T_ + t];          // L2-warm
      const bool msk = (tk != 0);
      const int rb = (gd*12 + gul*3)*64 + gb;
      float rz = recl[rb]        + bz1;
      float rr = recl[rb + 64]   + br1;
      float rh = recl[rb + 128]  + bh1;
      float xz = xpv[(gd*C3 +          gu)*128 + tk];   // L2-warm (cached after barrier 2)
      float xr = xpv[(gd*C3 +   U_  +  gu)*128 + tk];
      float xh = xpv[(gd*C3 + 2*U_  +  gu)*128 + tk];
      float z  = sigm(xz + rz);
      float rg = sigm(xr + rr);
      float th = tanh_(xh + rg*rh);
      float hnew = z*hprev + (1.f - z)*th;
      float hx = msk ? hnew : hprev;          // out_t == h_t (mask freezes both)
      hprev = hx;
      st_coh(&hn[(gd*1024 + gu)*64 + gb], hx);
      float* op = out + (gb*T_ + t)*U_ + gu;  // same-WG '=' then '+=': same CU/L2, barrier-ordered
      if (s < 64) *op = hx; else *op += hx;
    }
    wg_barrier(ctr, (++bar)*NWG);
  }
}

extern "C" void kernel_launch(void* const* d_in, const int* in_sizes, int n_in,
                              void* d_out, int out_size, void* d_ws, size_t ws_size,
                              hipStream_t stream) {
  const int*   tok = (const int*)  d_in[0];
  const float* emb = (const float*)d_in[1];
  const float* Wf  = (const float*)d_in[2];
  const float* Uf  = (const float*)d_in[3];
  const float* bfp = (const float*)d_in[4];
  const float* Wb  = (const float*)d_in[5];
  const float* Ub  = (const float*)d_in[6];
  const float* bbp = (const float*)d_in[7];
  float* outp = (float*)d_out;
  float* wsp  = (float*)d_ws;

  hipFuncSetAttribute((const void*)enc_kernel,
                      hipFuncAttributeMaxDynamicSharedMemorySize, SMEM_BYTES);

  // zero the barrier counter (ws is re-poisoned to 0xAA before every launch)
  hipMemsetAsync((char*)d_ws + CTR_OFF*sizeof(float), 0, 64, stream);

  void* args[] = { (void*)&tok, (void*)&emb, (void*)&Wf, (void*)&Uf, (void*)&bfp,
                   (void*)&Wb, (void*)&Ub, (void*)&bbp, (void*)&outp, (void*)&wsp };
  hipLaunchCooperativeKernel((const void*)enc_kernel, dim3(NWG), dim3(NT),
                             args, SMEM_BYTES, stream);
}